// Round 13
// baseline (113.411 us; speedup 1.0000x reference)
//
#include <hip/hip_runtime.h>
#include <math.h>

#define NN 8
#define CC 4
#define FF 257
#define TT 2000
#define BB 8
#define MM 80
#define EPSF 1e-5f
#define T4N 500    // TT/4
#define PTILE 32   // t per block in k_proj
#define PSTR 260   // LDS row stride
#define PCHUNK 63  // ceil(2000/32)
#define SBIN 256   // s_buf bins
#define BBIN 63    // BN bins (= chunk)

typedef float v2f __attribute__((ext_vector_type(2)));

__device__ __forceinline__ float fsqrt_fast(float x) { return __builtin_amdgcn_sqrtf(x); }
__device__ __forceinline__ float flog_fast(float x)  { return __builtin_amdgcn_logf(x) * 0.69314718055994531f; }
__device__ __forceinline__ v2f sqrt2(v2f m) {
    v2f r; r.x = __builtin_amdgcn_sqrtf(m.x); r.y = __builtin_amdgcn_sqrtf(m.y); return r;
}

// ---------------- kernel 1: beamform q,k, reduce s partials; side-job: repack proj_w ----
// grid (NN*FF, 2), block 256. Each thread: 4 consecutive t via float4, pk-math.
__global__ __launch_bounds__(256) void k_beam_s(
    const float* __restrict__ xr_g, const float* __restrict__ xi_g,
    const float* __restrict__ wq_r, const float* __restrict__ wq_i,
    const float* __restrict__ wk_r, const float* __restrict__ wk_i,
    float* __restrict__ s_buf,
    const float* __restrict__ proj_w, float* __restrict__ proj_pad)
{
    int nf = blockIdx.x;
    // folded k_prep: y==0 blocks 0..81 repack proj_w into padded stride-260
    if (blockIdx.y == 0) {
        int i = nf*256 + threadIdx.x;
        if (i < MM*260) {
            int m = i/260, fp = i%260;
            proj_pad[i] = (fp < FF) ? proj_w[m*FF + fp] : 0.f;
        }
    }

    int n = nf / FF, f = nf % FF;
    int t4 = blockIdx.y * 256 + threadIdx.x;

    float part[BB];
#pragma unroll
    for (int b = 0; b < BB; ++b) part[b] = 0.f;

    if (t4 < T4N) {
        const float* xr_base = xr_g + ((size_t)(n*CC)*FF + f) * TT + t4*4;
        const float* xi_base = xi_g + ((size_t)(n*CC)*FF + f) * TT + t4*4;
        v2f xr2[CC][2], xi2[CC][2];
#pragma unroll
        for (int c = 0; c < CC; ++c) {
            float4 r4 = *reinterpret_cast<const float4*>(xr_base + (size_t)c*FF*TT);
            float4 i4 = *reinterpret_cast<const float4*>(xi_base + (size_t)c*FF*TT);
            xr2[c][0].x = r4.x; xr2[c][0].y = r4.y; xr2[c][1].x = r4.z; xr2[c][1].y = r4.w;
            xi2[c][0].x = i4.x; xi2[c][0].y = i4.y; xi2[c][1].x = i4.z; xi2[c][1].y = i4.w;
        }

        const float4 qr4 = *reinterpret_cast<const float4*>(&wq_r[f*CC]);  // f block-uniform
        const float4 qi4 = *reinterpret_cast<const float4*>(&wq_i[f*CC]);

        v2f qq[2];
#pragma unroll
        for (int p = 0; p < 2; ++p) {
            v2f qr = xr2[0][p]*qr4.x + xr2[1][p]*qr4.y + xr2[2][p]*qr4.z + xr2[3][p]*qr4.w
                   - xi2[0][p]*qi4.x - xi2[1][p]*qi4.y - xi2[2][p]*qi4.z - xi2[3][p]*qi4.w;
            v2f qi = xi2[0][p]*qr4.x + xi2[1][p]*qr4.y + xi2[2][p]*qr4.z + xi2[3][p]*qr4.w
                   + xr2[0][p]*qi4.x + xr2[1][p]*qi4.y + xr2[2][p]*qi4.z + xr2[3][p]*qi4.w;
            qq[p] = qr*qr + qi*qi + EPSF;
        }

#pragma unroll
        for (int b = 0; b < BB; ++b) {
            const float4 wr4 = *reinterpret_cast<const float4*>(&wk_r[(f*BB + b)*CC]);
            const float4 wi4 = *reinterpret_cast<const float4*>(&wk_i[(f*BB + b)*CC]);
            v2f acc; acc.x = 0.f; acc.y = 0.f;
#pragma unroll
            for (int p = 0; p < 2; ++p) {
                v2f kr = xr2[0][p]*wr4.x + xr2[1][p]*wr4.y + xr2[2][p]*wr4.z + xr2[3][p]*wr4.w
                       - xi2[0][p]*wi4.x - xi2[1][p]*wi4.y - xi2[2][p]*wi4.z - xi2[3][p]*wi4.w;
                v2f ki = xi2[0][p]*wr4.x + xi2[1][p]*wr4.y + xi2[2][p]*wr4.z + xi2[3][p]*wr4.w
                       + xr2[0][p]*wi4.x + xr2[1][p]*wi4.y + xr2[2][p]*wi4.z + xr2[3][p]*wi4.w;
                v2f kk = kr*kr + ki*ki + EPSF;
                acc += sqrt2(qq[p] * kk);   // sqrt(qq)*sqrt(kk) fused
            }
            part[b] = acc.x + acc.y;
        }
    }

    __shared__ float red[4][BB];
    int lane = threadIdx.x & 63, wv = threadIdx.x >> 6;
#pragma unroll
    for (int b = 0; b < BB; ++b) {
        float v = part[b];
#pragma unroll
        for (int m = 32; m >= 1; m >>= 1) v += __shfl_xor(v, m);
        if (lane == 0) red[wv][b] = v;
    }
    __syncthreads();
    if (threadIdx.x < BB) {
        float v = red[0][threadIdx.x] + red[1][threadIdx.x]
                + red[2][threadIdx.x] + red[3][threadIdx.x];
        int bin = (blockIdx.x * 2 + blockIdx.y) & (SBIN - 1);
        atomicAdd(&s_buf[bin*64 + n*BB + threadIdx.x], v);
    }
}

// ---------------- kernel 1b: softmax over B per n (sums 256 bins) ----------------
__global__ void k_softmax(const float* __restrict__ s_buf, float* __restrict__ w_buf)
{
    int tid = threadIdx.x;
    if (tid < NN*BB) {
        float v = 0.f;
#pragma unroll 8
        for (int j = 0; j < SBIN; ++j) v += s_buf[j*64 + tid];
        v *= (1.0f / TT);
        float mx = v;
#pragma unroll
        for (int m = 4; m >= 1; m >>= 1) mx = fmaxf(mx, __shfl_xor(mx, m));
        float e = expf(v - mx);
        float sm = e;
#pragma unroll
        for (int m = 4; m >= 1; m >>= 1) sm += __shfl_xor(sm, m);
        w_buf[tid] = e / sm;
    }
}

// ---------------- kernel 2: v[n,f,t] = sum_b w_b * |beam_v| (R10-proven core) ----------------
__global__ __launch_bounds__(256) void k_vcompute(
    const float* __restrict__ xr_g, const float* __restrict__ xi_g,
    const float* __restrict__ wv_r, const float* __restrict__ wv_i,
    const float* __restrict__ w_buf, float* __restrict__ vbuf)
{
    int nf = blockIdx.x;
    int n = nf / FF, f = nf % FF;
    int t4 = blockIdx.y * 256 + threadIdx.x;
    if (t4 >= T4N) return;

    const float* xr_base = xr_g + ((size_t)(n*CC)*FF + f) * TT + t4*4;
    const float* xi_base = xi_g + ((size_t)(n*CC)*FF + f) * TT + t4*4;
    v2f xr2[CC][2], xi2[CC][2];
#pragma unroll
    for (int c = 0; c < CC; ++c) {
        float4 r4 = *reinterpret_cast<const float4*>(xr_base + (size_t)c*FF*TT);
        float4 i4 = *reinterpret_cast<const float4*>(xi_base + (size_t)c*FF*TT);
        xr2[c][0].x = r4.x; xr2[c][0].y = r4.y; xr2[c][1].x = r4.z; xr2[c][1].y = r4.w;
        xi2[c][0].x = i4.x; xi2[c][0].y = i4.y; xi2[c][1].x = i4.z; xi2[c][1].y = i4.w;
    }

    v2f vo[2];
    vo[0].x = 0.f; vo[0].y = 0.f; vo[1].x = 0.f; vo[1].y = 0.f;
#pragma unroll
    for (int b = 0; b < BB; ++b) {
        float wn = w_buf[n*BB + b];                      // n uniform -> scalar
        const float4 wr4 = *reinterpret_cast<const float4*>(&wv_r[(f*BB + b)*CC]);
        const float4 wi4 = *reinterpret_cast<const float4*>(&wv_i[(f*BB + b)*CC]);
#pragma unroll
        for (int p = 0; p < 2; ++p) {
            v2f vr = xr2[0][p]*wr4.x + xr2[1][p]*wr4.y + xr2[2][p]*wr4.z + xr2[3][p]*wr4.w
                   - xi2[0][p]*wi4.x - xi2[1][p]*wi4.y - xi2[2][p]*wi4.z - xi2[3][p]*wi4.w;
            v2f vi = xi2[0][p]*wr4.x + xi2[1][p]*wr4.y + xi2[2][p]*wr4.z + xi2[3][p]*wr4.w
                   + xr2[0][p]*wi4.x + xr2[1][p]*wi4.y + xr2[2][p]*wi4.z + xr2[3][p]*wi4.w;
            vo[p] += wn * sqrt2(vr*vr + vi*vi + EPSF);
        }
    }
    float4 o; o.x = vo[0].x; o.y = vo[0].y; o.z = vo[1].x; o.w = vo[1].y;
    *reinterpret_cast<float4*>(&vbuf[((size_t)(n*FF + f))*TT + t4*4]) = o;
}

// ---------------- kernel 3: project, relu, log, BN partials (t-register-blocked) ----------------
// grid (NN, 63), block 256. BN bin = chunk (63 bins) -> only 8 n-blocks alias an address.
__global__ __launch_bounds__(256) void k_proj(
    const float* __restrict__ vbuf, const float* __restrict__ proj_pad,
    float* __restrict__ out, double* __restrict__ bn_sum, double* __restrict__ bn_sumsq)
{
    __shared__ float v_lds[PTILE * PSTR];
    int n = blockIdx.x, chunk = blockIdx.y;
    int t0 = chunk * PTILE;
    int tid = threadIdx.x;
    bool full = (t0 + PTILE <= TT);

    if (tid < PTILE*3) {
        int t = tid / 3, fp = FF + tid % 3;
        v_lds[t*PSTR + fp] = 0.f;
    }

    int tq = tid & 7, fi = tid >> 3;
    bool tqv = full || (tq < 4);
#pragma unroll
    for (int k = 0; k < 8; ++k) {
        int f = fi + 32*k;
        float4 vv;
        if (tqv) vv = *reinterpret_cast<const float4*>(&vbuf[((size_t)(n*FF + f))*TT + t0 + tq*4]);
        else { vv.x = 0.f; vv.y = 0.f; vv.z = 0.f; vv.w = 0.f; }
        v_lds[(tq*4 + 0)*PSTR + f] = vv.x;
        v_lds[(tq*4 + 1)*PSTR + f] = vv.y;
        v_lds[(tq*4 + 2)*PSTR + f] = vv.z;
        v_lds[(tq*4 + 3)*PSTR + f] = vv.w;
    }
    if (tid < 8) {
        float4 vv;
        if (full || tid < 4) vv = *reinterpret_cast<const float4*>(&vbuf[((size_t)(n*FF + 256))*TT + t0 + tid*4]);
        else { vv.x = 0.f; vv.y = 0.f; vv.z = 0.f; vv.w = 0.f; }
        v_lds[(tid*4 + 0)*PSTR + 256] = vv.x;
        v_lds[(tid*4 + 1)*PSTR + 256] = vv.y;
        v_lds[(tid*4 + 2)*PSTR + 256] = vv.z;
        v_lds[(tid*4 + 3)*PSTR + 256] = vv.w;
    }
    __syncthreads();

    int tl = tid & 7, fg = tid >> 3;
    int mstart = (fg >> 1)*5 + ((fg & 1) ? 3 : 0);
    bool three = !(fg & 1);

    v2f acc[3][4];
#pragma unroll
    for (int mi = 0; mi < 3; ++mi)
#pragma unroll
        for (int j = 0; j < 4; ++j) { acc[mi][j].x = 0.f; acc[mi][j].y = 0.f; }

    const float* pp = proj_pad + mstart*260;
#pragma unroll 2
    for (int f4 = 0; f4 < 260; f4 += 4) {
        float4 p0 = *reinterpret_cast<const float4*>(&pp[f4]);
        float4 p1 = *reinterpret_cast<const float4*>(&pp[260 + f4]);
        v2f q00, q01, q10, q11, q20, q21;
        q00.x = p0.x; q00.y = p0.y; q01.x = p0.z; q01.y = p0.w;
        q10.x = p1.x; q10.y = p1.y; q11.x = p1.z; q11.y = p1.w;
        if (three) {
            float4 p2 = *reinterpret_cast<const float4*>(&pp[520 + f4]);
            q20.x = p2.x; q20.y = p2.y; q21.x = p2.z; q21.y = p2.w;
        }
#pragma unroll
        for (int j = 0; j < 4; ++j) {
            float4 vv = *reinterpret_cast<const float4*>(&v_lds[(tl + 8*j)*PSTR + f4]);
            v2f v0, v1;
            v0.x = vv.x; v0.y = vv.y; v1.x = vv.z; v1.y = vv.w;
            acc[0][j] += v0*q00 + v1*q01;
            acc[1][j] += v0*q10 + v1*q11;
            if (three) acc[2][j] += v0*q20 + v1*q21;
        }
    }

    int bin = chunk;   // 63 distinct bins
#pragma unroll
    for (int mi = 0; mi < 3; ++mi) {
        if (mi == 2 && !three) break;
        int m = mstart + mi;
        float s1 = 0.f, s2 = 0.f;
#pragma unroll
        for (int j = 0; j < 4; ++j) {
            int t = t0 + tl + 8*j;
            if (t < TT) {
                float r = flog_fast(fmaxf(acc[mi][j].x + acc[mi][j].y, 0.f) + EPSF);
                s1 += r; s2 += r*r;
                out[((size_t)n*TT + t)*MM + m] = r;
            }
        }
#pragma unroll
        for (int msk = 4; msk >= 1; msk >>= 1) {
            s1 += __shfl_xor(s1, msk);
            s2 += __shfl_xor(s2, msk);
        }
        if (tl == 0) {
            atomicAdd(&bn_sum[bin*MM + m], (double)s1);
            atomicAdd(&bn_sumsq[bin*MM + m], (double)s2);
        }
    }
}

// ---------------- kernel 4: BN finalize-in-LDS + apply (merged) ----------------
__global__ __launch_bounds__(256) void k_bnfuse(float* __restrict__ out,
                                                const double* __restrict__ bn_sum,
                                                const double* __restrict__ bn_sumsq,
                                                const float* __restrict__ gamma,
                                                const float* __restrict__ beta)
{
    __shared__ float sc_l[MM], sh_l[MM];
    int tid = threadIdx.x;
    if (tid < MM) {
        double s = 0.0, q = 0.0;
#pragma unroll 9
        for (int j = 0; j < BBIN; ++j) { s += bn_sum[j*MM + tid]; q += bn_sumsq[j*MM + tid]; }
        double inv = 1.0 / (double)(NN * TT);
        double mu = s * inv;
        double var = q * inv - mu * mu;
        float sc = gamma[tid] * rsqrtf((float)var + EPSF);
        sc_l[tid] = sc;
        sh_l[tid] = beta[tid] - (float)mu * sc;
    }
    __syncthreads();

    int i4 = blockIdx.x * 256 + tid;
    if (i4 < NN*TT*MM/4) {
        float4 v = *reinterpret_cast<const float4*>(&out[i4*4]);
        int m = (i4*4) % MM;
        v.x = v.x*sc_l[m+0] + sh_l[m+0];
        v.y = v.y*sc_l[m+1] + sh_l[m+1];
        v.z = v.z*sc_l[m+2] + sh_l[m+2];
        v.w = v.w*sc_l[m+3] + sh_l[m+3];
        *reinterpret_cast<float4*>(&out[i4*4]) = v;
    }
}

extern "C" void kernel_launch(void* const* d_in, const int* in_sizes, int n_in,
                              void* d_out, int out_size, void* d_ws, size_t ws_size,
                              hipStream_t stream)
{
    const float* x_real   = (const float*)d_in[0];
    const float* x_imag   = (const float*)d_in[1];
    const float* wq_r     = (const float*)d_in[2];
    const float* wq_i     = (const float*)d_in[3];
    const float* wk_r     = (const float*)d_in[4];
    const float* wk_i     = (const float*)d_in[5];
    const float* wv_r     = (const float*)d_in[6];
    const float* wv_i     = (const float*)d_in[7];
    const float* proj_w   = (const float*)d_in[8];
    const float* bn_gamma = (const float*)d_in[9];
    const float* bn_beta  = (const float*)d_in[10];
    float* out = (float*)d_out;

    char* ws = (char*)d_ws;
    float*  s_buf    = (float*)(ws + 0);        // 256 bins x 64 floats (65536 B)
    float*  w_buf    = (float*)(ws + 65536);    // 64 floats (256 B)
    double* bn_sum   = (double*)(ws + 65792);   // 63 bins x 80 doubles (40320 B)
    double* bn_sumsq = (double*)(ws + 106112);  // 63 bins x 80 doubles (40320 B)
    float*  proj_pad = (float*)(ws + 146432);   // 80*260 floats (83200 B)
    float*  vbuf     = (float*)(ws + 229632);   // 8*257*2000 floats (16448000 B)

    hipMemsetAsync(d_ws, 0, 146432, stream);    // zero s_buf + w_buf + bn bins

    dim3 g1(NN*FF, 2);
    k_beam_s<<<g1, 256, 0, stream>>>(x_real, x_imag, wq_r, wq_i, wk_r, wk_i, s_buf,
                                     proj_w, proj_pad);

    k_softmax<<<1, 64, 0, stream>>>(s_buf, w_buf);

    k_vcompute<<<g1, 256, 0, stream>>>(x_real, x_imag, wv_r, wv_i, w_buf, vbuf);

    dim3 g3(NN, PCHUNK);
    k_proj<<<g3, 256, 0, stream>>>(vbuf, proj_pad, out, bn_sum, bn_sumsq);

    k_bnfuse<<<(NN*TT*MM/4 + 255)/256, 256, 0, stream>>>(out, bn_sum, bn_sumsq,
                                                          bn_gamma, bn_beta);
}

// Round 16
// 97.951 us; speedup vs baseline: 1.1578x; 1.1578x over previous
//
#include <hip/hip_runtime.h>
#include <math.h>

#define NN 8
#define CC 4
#define FF 257
#define TT 2000
#define BB 8
#define MM 80
#define EPSF 1e-5f
#define T4N 500    // TT/4
#define PTILE 32   // t per block in k_proj
#define PSTR 260   // LDS row stride
#define PCHUNK 63  // ceil(2000/32)

typedef float v2f __attribute__((ext_vector_type(2)));

__device__ __forceinline__ float fsqrt_fast(float x) { return __builtin_amdgcn_sqrtf(x); }
__device__ __forceinline__ float flog_fast(float x)  { return __builtin_amdgcn_logf(x) * 0.69314718055994531f; }
__device__ __forceinline__ v2f sqrt2(v2f m) {
    v2f r; r.x = __builtin_amdgcn_sqrtf(m.x); r.y = __builtin_amdgcn_sqrtf(m.y); return r;
}

// ---------------- kernel 1: beamform q,k, reduce s partials; side-job: repack proj_w ----
// grid (NN*FF), block 512 (one block per (n,f), covers all 500 t4 slots).
__global__ __launch_bounds__(512) void k_beam_s(
    const float* __restrict__ xr_g, const float* __restrict__ xi_g,
    const float* __restrict__ wq_r, const float* __restrict__ wq_i,
    const float* __restrict__ wk_r, const float* __restrict__ wk_i,
    float* __restrict__ s_buf,
    const float* __restrict__ proj_w, float* __restrict__ proj_pad)
{
    int nf = blockIdx.x;
    int tid = threadIdx.x;

    // folded k_prep: blocks 0..40 repack proj_w into padded stride-260
    {
        int i = nf*512 + tid;
        if (i < MM*260) {
            int m = i/260, fp = i%260;
            proj_pad[i] = (fp < FF) ? proj_w[m*FF + fp] : 0.f;
        }
    }

    int n = nf / FF, f = nf % FF;
    int t4 = tid;

    float part[BB];
#pragma unroll
    for (int b = 0; b < BB; ++b) part[b] = 0.f;

    if (t4 < T4N) {
        const float* xr_base = xr_g + ((size_t)(n*CC)*FF + f) * TT + t4*4;
        const float* xi_base = xi_g + ((size_t)(n*CC)*FF + f) * TT + t4*4;
        v2f xr2[CC][2], xi2[CC][2];
#pragma unroll
        for (int c = 0; c < CC; ++c) {
            float4 r4 = *reinterpret_cast<const float4*>(xr_base + (size_t)c*FF*TT);
            float4 i4 = *reinterpret_cast<const float4*>(xi_base + (size_t)c*FF*TT);
            xr2[c][0].x = r4.x; xr2[c][0].y = r4.y; xr2[c][1].x = r4.z; xr2[c][1].y = r4.w;
            xi2[c][0].x = i4.x; xi2[c][0].y = i4.y; xi2[c][1].x = i4.z; xi2[c][1].y = i4.w;
        }

        const float4 qr4 = *reinterpret_cast<const float4*>(&wq_r[f*CC]);  // f block-uniform
        const float4 qi4 = *reinterpret_cast<const float4*>(&wq_i[f*CC]);

        v2f qq[2];
#pragma unroll
        for (int p = 0; p < 2; ++p) {
            v2f qr = xr2[0][p]*qr4.x + xr2[1][p]*qr4.y + xr2[2][p]*qr4.z + xr2[3][p]*qr4.w
                   - xi2[0][p]*qi4.x - xi2[1][p]*qi4.y - xi2[2][p]*qi4.z - xi2[3][p]*qi4.w;
            v2f qi = xi2[0][p]*qr4.x + xi2[1][p]*qr4.y + xi2[2][p]*qr4.z + xi2[3][p]*qr4.w
                   + xr2[0][p]*qi4.x + xr2[1][p]*qi4.y + xr2[2][p]*qi4.z + xr2[3][p]*qi4.w;
            qq[p] = qr*qr + qi*qi + EPSF;
        }

#pragma unroll
        for (int b = 0; b < BB; ++b) {
            const float4 wr4 = *reinterpret_cast<const float4*>(&wk_r[(f*BB + b)*CC]);
            const float4 wi4 = *reinterpret_cast<const float4*>(&wk_i[(f*BB + b)*CC]);
            v2f acc; acc.x = 0.f; acc.y = 0.f;
#pragma unroll
            for (int p = 0; p < 2; ++p) {
                v2f kr = xr2[0][p]*wr4.x + xr2[1][p]*wr4.y + xr2[2][p]*wr4.z + xr2[3][p]*wr4.w
                       - xi2[0][p]*wi4.x - xi2[1][p]*wi4.y - xi2[2][p]*wi4.z - xi2[3][p]*wi4.w;
                v2f ki = xi2[0][p]*wr4.x + xi2[1][p]*wr4.y + xi2[2][p]*wr4.z + xi2[3][p]*wr4.w
                       + xr2[0][p]*wi4.x + xr2[1][p]*wi4.y + xr2[2][p]*wi4.z + xr2[3][p]*wi4.w;
                v2f kk = kr*kr + ki*ki + EPSF;
                acc += sqrt2(qq[p] * kk);   // sqrt(qq)*sqrt(kk) fused
            }
            part[b] = acc.x + acc.y;
        }
    }

    __shared__ float red[8][BB];
    int lane = tid & 63, wv = tid >> 6;
#pragma unroll
    for (int b = 0; b < BB; ++b) {
        float v = part[b];
#pragma unroll
        for (int m = 32; m >= 1; m >>= 1) v += __shfl_xor(v, m);
        if (lane == 0) red[wv][b] = v;
    }
    __syncthreads();
    if (tid < BB) {
        float v = 0.f;
#pragma unroll
        for (int w = 0; w < 8; ++w) v += red[w][tid];
        int bin = nf & 15;
        atomicAdd(&s_buf[bin*64 + n*BB + tid], v);
    }
}

// ---------------- kernel 2: v[n,f,t] = sum_b softmax(s)_b * |beam_v| ----------------
// grid (NN*FF, 2), block 256 (R10/R12-proven core, inline softmax).
__global__ __launch_bounds__(256) void k_vcompute(
    const float* __restrict__ xr_g, const float* __restrict__ xi_g,
    const float* __restrict__ wv_r, const float* __restrict__ wv_i,
    const float* __restrict__ s_buf, float* __restrict__ vbuf)
{
    int nf = blockIdx.x;
    int n = nf / FF, f = nf % FF;
    int t4 = blockIdx.y * 256 + threadIdx.x;
    if (t4 >= T4N) return;

    // inline softmax over B (uniform per block -> scalar unit)
    float wn[BB];
    {
        float sv[BB]; float mx = -1e30f;
#pragma unroll
        for (int b = 0; b < BB; ++b) {
            float v = 0.f;
#pragma unroll
            for (int j = 0; j < 16; ++j) v += s_buf[j*64 + n*BB + b];
            sv[b] = v * (1.0f / TT);
            mx = fmaxf(mx, sv[b]);
        }
        float sm = 0.f;
#pragma unroll
        for (int b = 0; b < BB; ++b) { sv[b] = expf(sv[b] - mx); sm += sv[b]; }
        float inv = 1.0f / sm;
#pragma unroll
        for (int b = 0; b < BB; ++b) wn[b] = sv[b] * inv;
    }

    const float* xr_base = xr_g + ((size_t)(n*CC)*FF + f) * TT + t4*4;
    const float* xi_base = xi_g + ((size_t)(n*CC)*FF + f) * TT + t4*4;
    v2f xr2[CC][2], xi2[CC][2];
#pragma unroll
    for (int c = 0; c < CC; ++c) {
        float4 r4 = *reinterpret_cast<const float4*>(xr_base + (size_t)c*FF*TT);
        float4 i4 = *reinterpret_cast<const float4*>(xi_base + (size_t)c*FF*TT);
        xr2[c][0].x = r4.x; xr2[c][0].y = r4.y; xr2[c][1].x = r4.z; xr2[c][1].y = r4.w;
        xi2[c][0].x = i4.x; xi2[c][0].y = i4.y; xi2[c][1].x = i4.z; xi2[c][1].y = i4.w;
    }

    v2f vo[2];
    vo[0].x = 0.f; vo[0].y = 0.f; vo[1].x = 0.f; vo[1].y = 0.f;
#pragma unroll
    for (int b = 0; b < BB; ++b) {
        const float4 wr4 = *reinterpret_cast<const float4*>(&wv_r[(f*BB + b)*CC]);
        const float4 wi4 = *reinterpret_cast<const float4*>(&wv_i[(f*BB + b)*CC]);
        float wnb = wn[b];
#pragma unroll
        for (int p = 0; p < 2; ++p) {
            v2f vr = xr2[0][p]*wr4.x + xr2[1][p]*wr4.y + xr2[2][p]*wr4.z + xr2[3][p]*wr4.w
                   - xi2[0][p]*wi4.x - xi2[1][p]*wi4.y - xi2[2][p]*wi4.z - xi2[3][p]*wi4.w;
            v2f vi = xi2[0][p]*wr4.x + xi2[1][p]*wr4.y + xi2[2][p]*wr4.z + xi2[3][p]*wr4.w
                   + xr2[0][p]*wi4.x + xr2[1][p]*wi4.y + xr2[2][p]*wi4.z + xr2[3][p]*wi4.w;
            vo[p] += wnb * sqrt2(vr*vr + vi*vi + EPSF);
        }
    }
    float4 o; o.x = vo[0].x; o.y = vo[0].y; o.z = vo[1].x; o.w = vo[1].y;
    *reinterpret_cast<float4*>(&vbuf[((size_t)(n*FF + f))*TT + t4*4]) = o;
}

// ---------------- kernel 3: project, relu, log, BN partials (R10-proven) ----------------
__global__ __launch_bounds__(256) void k_proj(
    const float* __restrict__ vbuf, const float* __restrict__ proj_pad,
    float* __restrict__ out, double* __restrict__ bn_sum, double* __restrict__ bn_sumsq)
{
    __shared__ float v_lds[PTILE * PSTR];
    int n = blockIdx.x, chunk = blockIdx.y;
    int t0 = chunk * PTILE;
    int tid = threadIdx.x;
    bool full = (t0 + PTILE <= TT);

    if (tid < PTILE*3) {
        int t = tid / 3, fp = FF + tid % 3;
        v_lds[t*PSTR + fp] = 0.f;
    }

    int tq = tid & 7, fi = tid >> 3;
    bool tqv = full || (tq < 4);
#pragma unroll
    for (int k = 0; k < 8; ++k) {
        int f = fi + 32*k;
        float4 vv;
        if (tqv) vv = *reinterpret_cast<const float4*>(&vbuf[((size_t)(n*FF + f))*TT + t0 + tq*4]);
        else { vv.x = 0.f; vv.y = 0.f; vv.z = 0.f; vv.w = 0.f; }
        v_lds[(tq*4 + 0)*PSTR + f] = vv.x;
        v_lds[(tq*4 + 1)*PSTR + f] = vv.y;
        v_lds[(tq*4 + 2)*PSTR + f] = vv.z;
        v_lds[(tq*4 + 3)*PSTR + f] = vv.w;
    }
    if (tid < 8) {
        float4 vv;
        if (full || tid < 4) vv = *reinterpret_cast<const float4*>(&vbuf[((size_t)(n*FF + 256))*TT + t0 + tid*4]);
        else { vv.x = 0.f; vv.y = 0.f; vv.z = 0.f; vv.w = 0.f; }
        v_lds[(tid*4 + 0)*PSTR + 256] = vv.x;
        v_lds[(tid*4 + 1)*PSTR + 256] = vv.y;
        v_lds[(tid*4 + 2)*PSTR + 256] = vv.z;
        v_lds[(tid*4 + 3)*PSTR + 256] = vv.w;
    }
    __syncthreads();

    int tl = tid & 7, fg = tid >> 3;
    int mstart = (fg >> 1)*5 + ((fg & 1) ? 3 : 0);
    bool three = !(fg & 1);

    v2f acc[3][4];
#pragma unroll
    for (int mi = 0; mi < 3; ++mi)
#pragma unroll
        for (int j = 0; j < 4; ++j) { acc[mi][j].x = 0.f; acc[mi][j].y = 0.f; }

    const float* pp = proj_pad + mstart*260;
#pragma unroll 2
    for (int f4 = 0; f4 < 260; f4 += 4) {
        float4 p0 = *reinterpret_cast<const float4*>(&pp[f4]);
        float4 p1 = *reinterpret_cast<const float4*>(&pp[260 + f4]);
        v2f q00, q01, q10, q11, q20, q21;
        q00.x = p0.x; q00.y = p0.y; q01.x = p0.z; q01.y = p0.w;
        q10.x = p1.x; q10.y = p1.y; q11.x = p1.z; q11.y = p1.w;
        if (three) {
            float4 p2 = *reinterpret_cast<const float4*>(&pp[520 + f4]);
            q20.x = p2.x; q20.y = p2.y; q21.x = p2.z; q21.y = p2.w;
        }
#pragma unroll
        for (int j = 0; j < 4; ++j) {
            float4 vv = *reinterpret_cast<const float4*>(&v_lds[(tl + 8*j)*PSTR + f4]);
            v2f v0, v1;
            v0.x = vv.x; v0.y = vv.y; v1.x = vv.z; v1.y = vv.w;
            acc[0][j] += v0*q00 + v1*q01;
            acc[1][j] += v0*q10 + v1*q11;
            if (three) acc[2][j] += v0*q20 + v1*q21;
        }
    }

    int bin = chunk & 15;
#pragma unroll
    for (int mi = 0; mi < 3; ++mi) {
        if (mi == 2 && !three) break;
        int m = mstart + mi;
        float s1 = 0.f, s2 = 0.f;
#pragma unroll
        for (int j = 0; j < 4; ++j) {
            int t = t0 + tl + 8*j;
            if (t < TT) {
                float r = flog_fast(fmaxf(acc[mi][j].x + acc[mi][j].y, 0.f) + EPSF);
                s1 += r; s2 += r*r;
                out[((size_t)n*TT + t)*MM + m] = r;
            }
        }
#pragma unroll
        for (int msk = 4; msk >= 1; msk >>= 1) {
            s1 += __shfl_xor(s1, msk);
            s2 += __shfl_xor(s2, msk);
        }
        if (tl == 0) {
            atomicAdd(&bn_sum[bin*MM + m], (double)s1);
            atomicAdd(&bn_sumsq[bin*MM + m], (double)s2);
        }
    }
}

// ---------------- kernel 4: BN finalize-in-LDS + apply (merged) ----------------
__global__ __launch_bounds__(256) void k_bnfuse(float* __restrict__ out,
                                                const double* __restrict__ bn_sum,
                                                const double* __restrict__ bn_sumsq,
                                                const float* __restrict__ gamma,
                                                const float* __restrict__ beta)
{
    __shared__ float sc_l[MM], sh_l[MM];
    int tid = threadIdx.x;
    if (tid < MM) {
        double s = 0.0, q = 0.0;
#pragma unroll
        for (int j = 0; j < 16; ++j) { s += bn_sum[j*MM + tid]; q += bn_sumsq[j*MM + tid]; }
        double inv = 1.0 / (double)(NN * TT);
        double mu = s * inv;
        double var = q * inv - mu * mu;
        float sc = gamma[tid] * rsqrtf((float)var + EPSF);
        sc_l[tid] = sc;
        sh_l[tid] = beta[tid] - (float)mu * sc;
    }
    __syncthreads();

    int i4 = blockIdx.x * 256 + tid;
    if (i4 < NN*TT*MM/4) {
        float4 v = *reinterpret_cast<const float4*>(&out[i4*4]);
        int m = (i4*4) % MM;
        v.x = v.x*sc_l[m+0] + sh_l[m+0];
        v.y = v.y*sc_l[m+1] + sh_l[m+1];
        v.z = v.z*sc_l[m+2] + sh_l[m+2];
        v.w = v.w*sc_l[m+3] + sh_l[m+3];
        *reinterpret_cast<float4*>(&out[i4*4]) = v;
    }
}

extern "C" void kernel_launch(void* const* d_in, const int* in_sizes, int n_in,
                              void* d_out, int out_size, void* d_ws, size_t ws_size,
                              hipStream_t stream)
{
    const float* x_real   = (const float*)d_in[0];
    const float* x_imag   = (const float*)d_in[1];
    const float* wq_r     = (const float*)d_in[2];
    const float* wq_i     = (const float*)d_in[3];
    const float* wk_r     = (const float*)d_in[4];
    const float* wk_i     = (const float*)d_in[5];
    const float* wv_r     = (const float*)d_in[6];
    const float* wv_i     = (const float*)d_in[7];
    const float* proj_w   = (const float*)d_in[8];
    const float* bn_gamma = (const float*)d_in[9];
    const float* bn_beta  = (const float*)d_in[10];
    float* out = (float*)d_out;

    char* ws = (char*)d_ws;
    float*  s_buf    = (float*)(ws + 0);        // 16 bins x 64 floats (4096 B)
    double* bn_sum   = (double*)(ws + 8192);    // 16 bins x 80 doubles (10240 B)
    double* bn_sumsq = (double*)(ws + 18432);   // 16 bins x 80 doubles (10240 B)
    float*  proj_pad = (float*)(ws + 28672);    // 80*260 floats (83200 B)
    float*  vbuf     = (float*)(ws + 112640);   // 8*257*2000 floats (16448000 B)

    hipMemsetAsync(d_ws, 0, 28672, stream);     // zero s_buf + bn bins

    k_beam_s<<<NN*FF, 512, 0, stream>>>(x_real, x_imag, wq_r, wq_i, wk_r, wk_i, s_buf,
                                        proj_w, proj_pad);

    dim3 g2(NN*FF, 2);
    k_vcompute<<<g2, 256, 0, stream>>>(x_real, x_imag, wv_r, wv_i, s_buf, vbuf);

    dim3 g3(NN, PCHUNK);
    k_proj<<<g3, 256, 0, stream>>>(vbuf, proj_pad, out, bn_sum, bn_sumsq);

    k_bnfuse<<<(NN*TT*MM/4 + 255)/256, 256, 0, stream>>>(out, bn_sum, bn_sumsq,
                                                          bn_gamma, bn_beta);
}